// Round 8
// baseline (365.660 us; speedup 1.0000x reference)
//
#include <hip/hip_runtime.h>
#include <hip/hip_bf16.h>

// Problem constants: B=4, C=128, Cq=16, W=H=64, N=4096.
// ws layout (ushort): qT bf16 [4][4096][16] @0, kT bf16 [4][4096][16] @262144,
//                     v  bf16 [4][128][4096] @524288
// d_out: out[4][128][4096] fp32, then attention[4][4096][4096] fp32

typedef __attribute__((ext_vector_type(8))) short short8;
typedef __attribute__((ext_vector_type(16))) float float16;
typedef __attribute__((ext_vector_type(4))) float floatx4;

__device__ __forceinline__ ushort f2bf(float f) {
  union { float f; uint u; } v; v.f = f;
  return (ushort)((v.u + 0x7FFFu + ((v.u >> 16) & 1u)) >> 16);  // RNE
}

// Barrier that waits ONLY on LDS ops (lgkmcnt), not the global store stream.
// Critical here: writer waves' stores must stay in flight across barriers.
#define LDS_BARRIER()                                             \
  do {                                                            \
    __builtin_amdgcn_sched_barrier(0);                            \
    asm volatile("s_waitcnt lgkmcnt(0)" ::: "memory");            \
    __builtin_amdgcn_sched_barrier(0);                            \
    __builtin_amdgcn_s_barrier();                                 \
    __builtin_amdgcn_sched_barrier(0);                            \
  } while (0)

// ---------------- Kernel 1: QKV projections (unchanged, verified) ----------
__global__ __launch_bounds__(512, 2) void qkv_kernel(
    const float* __restrict__ x,
    const float* __restrict__ wq, const float* __restrict__ bq,
    const float* __restrict__ wk, const float* __restrict__ bk,
    const float* __restrict__ wv, const float* __restrict__ bv,
    ushort* __restrict__ qT, ushort* __restrict__ kT, ushort* __restrict__ vo) {
  __shared__ float xs[128 * 64];
  const int nt = blockIdx.x, b = blockIdx.y;
  const int n0 = nt * 64;
  const float* xb = x + (size_t)b * 524288 + n0;
  for (int idx = threadIdx.x; idx < 8192; idx += 512) {
    int c = idx >> 6, n = idx & 63;
    xs[idx] = xb[(size_t)c * 4096 + n];
  }
  __syncthreads();
  const int n = threadIdx.x & 63;
  const int og = __builtin_amdgcn_readfirstlane((int)(threadIdx.x >> 6)); // 0..7
  float acc[20];
#pragma unroll
  for (int i = 0; i < 20; i++) {
    int o = og + 8 * i;
    acc[i] = (i < 2) ? bq[o] : (i < 4) ? bk[o - 16] : bv[o - 32];
  }
#pragma unroll 4
  for (int c = 0; c < 128; c++) {
    float xr = xs[c * 64 + n];
#pragma unroll
    for (int i = 0; i < 20; i++) {
      int o = og + 8 * i;
      const float* wr = (i < 2) ? (wq + o * 128)
                      : (i < 4) ? (wk + (o - 16) * 128)
                                : (wv + (o - 32) * 128);
      acc[i] += wr[c] * xr;
    }
  }
  const size_t pos = (size_t)b * 4096 + n0 + n;
#pragma unroll
  for (int i = 0; i < 20; i++) {
    int o = og + 8 * i;
    if (i < 2)      qT[pos * 16 + o]      = f2bf(acc[i]);
    else if (i < 4) kT[pos * 16 + o - 16] = f2bf(acc[i]);
    else vo[(size_t)b * 524288 + (size_t)(o - 32) * 4096 + n0 + n] = f2bf(acc[i]);
  }
}

// ---------------- Kernel 2: fused attn, WAVE-SPECIALIZED -------------------
// 512 blocks x 512 thr (8 waves), 2 blocks/CU. Waves 0-3 = COMPUTE (E, PV,
// out-epilogue; zero global stores -> their kf/vrow/x loads never vmcnt-wait
// behind the attn store stream). Waves 4-7 = WRITERS (ds_read P fp32 from
// LDS, stream to attn + zero-fill; no VMEM loads after phase 1 -> their
// stores queue deep and drain continuously under compute). vmcnt is an
// in-order load+store counter on CDNA: mixing loads into a store stream
// forces full store drains at every load use — the specialization removes
// that coupling per-wave.
__global__ __launch_bounds__(512, 4) void fused_attn_kernel(
    const ushort* __restrict__ qT, const ushort* __restrict__ kT,
    const ushort* __restrict__ vws, const float* __restrict__ x,
    const float* __restrict__ g,
    float* __restrict__ attn, float* __restrict__ out) {
  __shared__ __align__(16) ushort Pt[4][32 * 72];   // 18,432 B (bf16 P for PV)
  __shared__ __align__(16) float Pf[4][32 * 64];    // 32,768 B (fp32 P for writers)
  __shared__ __align__(16) float red[32][8];        // 1 KB
  const int bx = blockIdx.x;            // 0..511
  const int b = bx & 3;
  const int v_ = bx >> 2;               // 0..127
  const int half = v_ & 1;
  const int u = v_ >> 1;                // 0..63
  const int rb = (u < 32) ? u : 95 - u; // CU-mate load balancing
  const int S = rb + 1;
  const int lane = threadIdx.x & 63;
  const int w = __builtin_amdgcn_readfirstlane((int)(threadIdx.x >> 6)); // 0..7
  const int role = w >> 2;              // 0 = compute, 1 = writer
  const int q = w & 3;                  // strip slot / c-quadrant
  const int nblk = rb * 64 + half * 32;
  const int l31 = lane & 31;
  const int h = lane >> 5;
  const int hk = h * 8;
  const ushort* qb = qT + (size_t)b * 65536;
  const ushort* kb = kT + (size_t)b * 65536;
  const ushort* vp = vws + (size_t)b * 524288;
  float* ab = attn + (size_t)b * 16777216;

  // q A-fragment for this block's 32 rows: A[n=l31][d=hk..hk+7] — 4 VGPRs.
  const short8 qa = *(const short8*)(qb + (size_t)(nblk + l31) * 16 + hk);

  float16 zero16;
#pragma unroll
  for (int i = 0; i < 16; i++) zero16[i] = 0.f;

  // ---- Phase 1: denominators (all 8 waves, strips step 8; verified R7) ----
  float sume[16];
#pragma unroll
  for (int i = 0; i < 16; i++) sume[i] = 0.f;
  for (int s = w; s < S; s += 8) {
    const int m0 = s * 64;
#pragma unroll
    for (int mh = 0; mh < 2; mh++) {
      short8 kf = *(const short8*)(kb + (size_t)(m0 + mh * 32 + l31) * 16 + hk);
      float16 e = __builtin_amdgcn_mfma_f32_32x32x16_bf16(qa, kf, zero16, 0, 0, 0);
#pragma unroll
      for (int r = 0; r < 16; r++) sume[r] += __expf(e[r]);
    }
  }
#pragma unroll
  for (int r = 0; r < 16; r++) {
#pragma unroll
    for (int off = 1; off <= 16; off <<= 1)
      sume[r] += __shfl_xor(sume[r], off, 64);  // sum over 32 cols (l31 group)
  }
  if (l31 == 0) {
#pragma unroll
    for (int r = 0; r < 16; r++) {
      int row = (r & 3) + 8 * (r >> 2) + 4 * h;
      red[row][w] = sume[r];
    }
  }
  __syncthreads();
  float inv[16];
#pragma unroll
  for (int r = 0; r < 16; r++) {
    int row = (r & 3) + 8 * (r >> 2) + 4 * h;
    const float* pr = &red[row][0];
    float t = ((pr[0] + pr[1]) + (pr[2] + pr[3])) +
              ((pr[4] + pr[5]) + (pr[6] + pr[7]));
    inv[r] = 1.0f / t;
  }

  // ---- Phase 2: compute waves E->LDS + PV;  writer waves LDS->attn ----
  float16 acc = zero16;
  for (int s0 = 0; s0 < S; s0 += 4) {
    const int sl = (S - s0 < 4) ? (S - s0) : 4;
    if (role == 0 && q < sl) {
      const int m0 = (s0 + q) * 64;
      ushort* Pb = &Pt[q][0];
      float* Pc = &Pf[q][0];
#pragma unroll
      for (int mh = 0; mh < 2; mh++) {
        short8 kf = *(const short8*)(kb + (size_t)(m0 + mh * 32 + l31) * 16 + hk);
        float16 e = __builtin_amdgcn_mfma_f32_32x32x16_bf16(qa, kf, zero16, 0, 0, 0);
#pragma unroll
        for (int r = 0; r < 16; r++) {
          int row = (r & 3) + 8 * (r >> 2) + 4 * h;
          float p = __expf(e[r]) * inv[r];
          Pc[row * 64 + mh * 32 + l31] = p;          // fp32 for writers
          Pb[row * 72 + mh * 32 + l31] = f2bf(p);    // bf16 for PV
        }
      }
    }
    LDS_BARRIER();   // LDS handoff only; writer stores stay in flight

    if (role == 1 && q < sl) {
      // Writer wave: stream strip q's 32x64 fp32 tile to attn.
      // Per inst: 4 rows x 64 cols = 64 lanes x 16B. No VMEM loads here.
      const int m0 = (s0 + q) * 64;
      const int r4 = lane >> 4;          // 0..3
      const int c4 = (lane & 15) * 4;    // 0,4,...,60
#pragma unroll
      for (int i = 0; i < 8; i++) {
        int row = i * 4 + r4;
        floatx4 val = *(const floatx4*)&Pf[q][row * 64 + c4];
        *(floatx4*)(ab + (size_t)(nblk + row) * 4096 + m0 + c4) = val;
      }
    }
    if (role == 0) {
      for (int ss = 0; ss < sl; ss++) {
        const int m0 = (s0 + ss) * 64;
        const ushort* vrow = vp + (size_t)(q * 32 + l31) * 4096 + m0 + hk;
        const ushort* Pr = &Pt[ss][l31 * 72 + hk];
#pragma unroll
        for (int kk = 0; kk < 4; kk++) {
          short8 a  = *(const short8*)(vrow + kk * 16);
          short8 bf = *(const short8*)(Pr + kk * 16);
          acc = __builtin_amdgcn_mfma_f32_32x32x16_bf16(a, bf, acc, 0, 0, 0);
        }
      }
    }
    LDS_BARRIER();   // protects Pt/Pf overwrite; no vmcnt drain
  }

  // ---- Epilogue ----
  if (role == 1) {
    // Writers: zero-fill masked attn region (wave q: rows q*8..q*8+7).
    const int M = S * 64;
    const int Z4 = (4096 - M) >> 2;
    const floatx4 z = {0.f, 0.f, 0.f, 0.f};
#pragma unroll
    for (int r = 0; r < 8; r++) {
      floatx4* dst = (floatx4*)(ab + (size_t)(nblk + q * 8 + r) * 4096 + M);
      for (int i4 = lane; i4 < Z4; i4 += 64) dst[i4] = z;
    }
  } else {
    // Compute waves: out = gamma * acc + x (c-quadrant = q).
    const float gamma = g[0];
#pragma unroll
    for (int reg = 0; reg < 16; reg++) {
      int row = (reg & 3) + 8 * (reg >> 2) + 4 * h;  // C/D row map
      int c = q * 32 + row;
      int n = nblk + l31;                            // C/D col = lane&31
      size_t off = (size_t)b * 524288 + (size_t)c * 4096 + n;
      out[off] = gamma * acc[reg] + x[off];
    }
  }
}

extern "C" void kernel_launch(void* const* d_in, const int* in_sizes, int n_in,
                              void* d_out, int out_size, void* d_ws, size_t ws_size,
                              hipStream_t stream) {
  const float* x  = (const float*)d_in[0];
  const float* wq = (const float*)d_in[1];
  const float* bq = (const float*)d_in[2];
  const float* wk = (const float*)d_in[3];
  const float* bk = (const float*)d_in[4];
  const float* wv = (const float*)d_in[5];
  const float* bv = (const float*)d_in[6];
  const float* gm = (const float*)d_in[7];
  float* out  = (float*)d_out;
  float* attn = out + 2097152;            // output 1: attention [4][4096][4096]
  ushort* qTw = (ushort*)d_ws;            // bf16 [4][4096][16]
  ushort* kTw = qTw + 262144;             // bf16 [4][4096][16]
  ushort* vws = qTw + 524288;             // bf16 [4][128][4096]

  qkv_kernel<<<dim3(64, 4), 512, 0, stream>>>(x, wq, bq, wk, bk, wv, bv, qTw, kTw, vws);
  fused_attn_kernel<<<dim3(512), 512, 0, stream>>>(qTw, kTw, vws, x, gm, attn, out);
}